// Round 8
// baseline (549.266 us; speedup 1.0000x reference)
//
#include <hip/hip_runtime.h>
#include <hip/hip_bf16.h>
#include <cstdint>
#include <cstddef>

typedef __attribute__((ext_vector_type(8))) short bf16x8;   // 8 bf16 in 4 VGPRs
typedef __attribute__((ext_vector_type(4))) float f32x4;

// Native bf16 convert (RNE) — compiler emits v_cvt_pk_bf16_f32 for pairs.
static __device__ __forceinline__ unsigned short f2bf(float f) {
    __hip_bfloat16 h = __float2bfloat16(f);
    return *reinterpret_cast<unsigned short*>(&h);
}

static __device__ __forceinline__ f32x4 mfma_bf16(bf16x8 a, bf16x8 b, f32x4 c) {
    return __builtin_amdgcn_mfma_f32_16x16x32_bf16(a, b, c, 0, 0, 0);
}

static __device__ __forceinline__ bf16x8 pack8(float4 a, float4 b) {
    bf16x8 f;
    f[0]=(short)f2bf(a.x); f[1]=(short)f2bf(a.y); f[2]=(short)f2bf(a.z); f[3]=(short)f2bf(a.w);
    f[4]=(short)f2bf(b.x); f[5]=(short)f2bf(b.y); f[6]=(short)f2bf(b.z); f[7]=(short)f2bf(b.w);
    return f;
}

// Branchless exact-erf GELU (A&S 7.1.26, |erf err| < 1.5e-7).
static __device__ __forceinline__ float gelu_erf(float v) {
    float s = v * 0.70710678118654752f;
    float a = fabsf(s);
    float t = __builtin_amdgcn_rcpf(1.0f + 0.3275911f * a);
    float poly = ((((1.061405429f * t - 1.453152027f) * t + 1.421413741f) * t
                   - 0.284496736f) * t + 0.254829592f) * t;
    float e = 1.0f - poly * __expf(-a * a);
    float erfv = copysignf(e, s);
    return 0.5f * v * (1.0f + erfv);
}

// async 16B global -> LDS (linear dest: wave-uniform base + lane*16)
static __device__ __forceinline__ void load_lds16(const unsigned short* g, unsigned short* l) {
    __builtin_amdgcn_global_load_lds(
        (const __attribute__((address_space(1))) unsigned int*)g,
        (__attribute__((address_space(3))) unsigned int*)l, 16, 0, 0);
}

// ---------------------------------------------------------------------------
// Attention (at its HBM floor ~43us): one block per (window, head).
// ---------------------------------------------------------------------------
__global__ __launch_bounds__(256) void attn_kernel(
    const float* __restrict__ q, const float* __restrict__ k,
    const float* __restrict__ v, const float* __restrict__ mask,
    float* __restrict__ xout)
{
    __shared__ unsigned short Qs[64][40];
    __shared__ unsigned short Ks[64][40];
    __shared__ unsigned short Vt[32][72];
    __shared__ unsigned short Ps[64][72];

    const int tid  = threadIdx.x;
    const int b    = blockIdx.x >> 3;
    const int h    = blockIdx.x & 7;
    const int lane = tid & 63;
    const int l15  = lane & 15;
    const int g    = lane >> 4;
    const int w    = tid >> 6;

    {
        int row = tid >> 2;
        int seg = tid & 3;
        size_t base = ((size_t)(b * 64 + row)) * 256 + h * 32 + seg * 8;

        float4 a0 = *(const float4*)(q + base);
        float4 a1 = *(const float4*)(q + base + 4);
        unsigned short* p = &Qs[row][seg * 8];
        p[0]=f2bf(a0.x); p[1]=f2bf(a0.y); p[2]=f2bf(a0.z); p[3]=f2bf(a0.w);
        p[4]=f2bf(a1.x); p[5]=f2bf(a1.y); p[6]=f2bf(a1.z); p[7]=f2bf(a1.w);

        a0 = *(const float4*)(k + base);
        a1 = *(const float4*)(k + base + 4);
        p = &Ks[row][seg * 8];
        p[0]=f2bf(a0.x); p[1]=f2bf(a0.y); p[2]=f2bf(a0.z); p[3]=f2bf(a0.w);
        p[4]=f2bf(a1.x); p[5]=f2bf(a1.y); p[6]=f2bf(a1.z); p[7]=f2bf(a1.w);

        a0 = *(const float4*)(v + base);
        a1 = *(const float4*)(v + base + 4);
        int c = seg * 8;
        Vt[c + 0][row] = f2bf(a0.x);
        Vt[c + 1][row] = f2bf(a0.y);
        Vt[c + 2][row] = f2bf(a0.z);
        Vt[c + 3][row] = f2bf(a0.w);
        Vt[c + 4][row] = f2bf(a1.x);
        Vt[c + 5][row] = f2bf(a1.y);
        Vt[c + 6][row] = f2bf(a1.z);
        Vt[c + 7][row] = f2bf(a1.w);
    }
    __syncthreads();

    f32x4 s[4];
    {
        bf16x8 aQ = *(const bf16x8*)&Qs[w * 16 + l15][g * 8];
        #pragma unroll
        for (int ct = 0; ct < 4; ++ct) {
            bf16x8 bK = *(const bf16x8*)&Ks[ct * 16 + l15][g * 8];
            f32x4 z = {0.f, 0.f, 0.f, 0.f};
            s[ct] = mfma_bf16(aQ, bK, z);
        }
    }

    const float* mbase = mask + (size_t)(b & 63) * 4096;
    const float INV = 0.17677669529663688f;
    float rsum[4];
    #pragma unroll
    for (int r = 0; r < 4; ++r) {
        int row = w * 16 + g * 4 + r;
        float pr[4];
        #pragma unroll
        for (int ct = 0; ct < 4; ++ct)
            pr[ct] = (s[ct][r] + mbase[row * 64 + ct * 16 + l15]) * INV;
        float m = fmaxf(fmaxf(pr[0], pr[1]), fmaxf(pr[2], pr[3]));
        #pragma unroll
        for (int off = 1; off < 16; off <<= 1)
            m = fmaxf(m, __shfl_xor(m, off));
        float sum = 0.f;
        #pragma unroll
        for (int ct = 0; ct < 4; ++ct) { pr[ct] = __expf(pr[ct] - m); sum += pr[ct]; }
        #pragma unroll
        for (int off = 1; off < 16; off <<= 1)
            sum += __shfl_xor(sum, off);
        rsum[r] = sum;
        #pragma unroll
        for (int ct = 0; ct < 4; ++ct)
            Ps[row][ct * 16 + l15] = f2bf(pr[ct]);
    }

    f32x4 o[2] = {};
    #pragma unroll
    for (int ks = 0; ks < 2; ++ks) {
        bf16x8 pa = *(const bf16x8*)&Ps[w * 16 + l15][ks * 32 + g * 8];
        #pragma unroll
        for (int n = 0; n < 2; ++n) {
            bf16x8 vb = *(const bf16x8*)&Vt[n * 16 + l15][ks * 32 + g * 8];
            o[n] = mfma_bf16(pa, vb, o[n]);
        }
    }

    #pragma unroll
    for (int n = 0; n < 2; ++n) {
        #pragma unroll
        for (int r = 0; r < 4; ++r) {
            int row = w * 16 + g * 4 + r;
            xout[((size_t)(b * 64 + row)) * 256 + h * 32 + n * 16 + l15] =
                o[n][r] / rsum[r];
        }
    }
}

// ---------------------------------------------------------------------------
// Weight prep, FRAGMENT-ORDERED, hidden-chunk = 32 (unchanged from r6).
// ---------------------------------------------------------------------------
__global__ __launch_bounds__(256) void prep_w1(const float* __restrict__ src,
                                               unsigned short* __restrict__ dst)
{
    __shared__ float tile[64][65];              // [k_local][n_local]
    const int kt = blockIdx.x, nb = blockIdx.y;
    const int t = threadIdx.x;
    const int r0 = t >> 4, c4 = (t & 15) * 4;
    #pragma unroll
    for (int p = 0; p < 4; ++p) {
        int kk = r0 + p * 16;
        float4 d = *(const float4*)(src + (size_t)(kt * 64 + kk) * 1024 + nb * 64 + c4);
        tile[kk][c4+0]=d.x; tile[kk][c4+1]=d.y; tile[kk][c4+2]=d.z; tile[kk][c4+3]=d.w;
    }
    __syncthreads();
    #pragma unroll
    for (int i = 0; i < 2; ++i) {
        int f = t + 256 * i;                    // 0..511
        int ksl = f >> 8;
        int ntg = (f >> 6) & 3;
        int gv  = (f >> 4) & 3;
        int l15v = f & 15;
        int n_local = ntg * 16 + l15v;
        int k_local = ksl * 32 + gv * 8;
        int c  = nb * 2 + (ntg >> 1);
        int nt = ntg & 1;
        int ks = kt * 2 + ksl;
        unsigned short tmp[8];
        #pragma unroll
        for (int e = 0; e < 8; ++e) tmp[e] = f2bf(tile[k_local + e][n_local]);
        size_t off = (size_t)c * 8192 + (size_t)((ks * 2 + nt) * 512)
                   + (gv * 16 + l15v) * 8;
        *(bf16x8*)(dst + off) = *(const bf16x8*)tmp;
    }
}

__global__ __launch_bounds__(256) void prep_w2(const float* __restrict__ src,
                                               unsigned short* __restrict__ dst)
{
    __shared__ float tile[64][65];              // [k_local][c_local]
    const int ob = blockIdx.x, kb = blockIdx.y;
    const int t = threadIdx.x;
    const int r0 = t >> 4, c4 = (t & 15) * 4;
    #pragma unroll
    for (int p = 0; p < 4; ++p) {
        int kk = r0 + p * 16;
        float4 d = *(const float4*)(src + (size_t)(kb * 64 + kk) * 256 + ob * 64 + c4);
        tile[kk][c4+0]=d.x; tile[kk][c4+1]=d.y; tile[kk][c4+2]=d.z; tile[kk][c4+3]=d.w;
    }
    __syncthreads();
    #pragma unroll
    for (int i = 0; i < 2; ++i) {
        int f = t + 256 * i;
        int ksl = f >> 8;
        int tq  = (f >> 6) & 3;
        int gv  = (f >> 4) & 3;
        int l15v = f & 15;
        int c_local = tq * 16 + l15v;
        int k_local = ksl * 32 + gv * 8;
        int c = kb * 2 + ksl;
        unsigned short tmp[8];
        #pragma unroll
        for (int e = 0; e < 8; ++e) tmp[e] = f2bf(tile[k_local + e][c_local]);
        size_t off = (size_t)c * 8192 + (size_t)((ob * 4 + tq) * 512)
                   + (gv * 16 + l15v) * 8;
        *(bf16x8*)(dst + off) = *(const bf16x8*)tmp;
    }
}

// ---------------------------------------------------------------------------
// Fused MLP v6: counted-vmcnt discipline (T4). Per chunk:
//   stage(next)  [4 DMA]
//   s_waitcnt vmcnt(4)  -- only current chunk's DMAs drained; next stays live
//   s_barrier
//   h-MFMA; bF hoist; bias(from LDS)+GELU -> Hs
//   s_waitcnt lgkmcnt(0); s_barrier  -- NO vm drain: DMA spans whole chunk
//   out-MFMA
// b1 lives in LDS (a global b1[] load in-loop would force vmcnt->0).
// ---------------------------------------------------------------------------
__global__ __launch_bounds__(512, 4) void mlp_fused(
    const float* __restrict__ xin, float* __restrict__ xio,
    const unsigned short* __restrict__ wt1, const float* __restrict__ b1,
    const unsigned short* __restrict__ wt2, const float* __restrict__ b2)
{
    __shared__ unsigned short w1c[2][8192];     // 16 KB per buf, frag-ordered
    __shared__ unsigned short w2c[2][8192];
    __shared__ unsigned short Hs[128][40];
    __shared__ float b1s[1024];

    const int tid  = threadIdx.x;
    const int lane = tid & 63;
    const int l15  = lane & 15;
    const int g    = lane >> 4;
    const int wid  = tid >> 6;                  // 0..7
    const int wmo  = wid >> 2, wno = wid & 3;   // out-phase wave grid 2x4
    const int fb   = (g * 16 + l15) * 8;        // frag offset: wave-contiguous 1KB

    const size_t rowbase = (size_t)blockIdx.x * 128;

    auto stage = [&](const unsigned short* gbase, unsigned short* lbase) {
        #pragma unroll
        for (int i = 0; i < 2; ++i) {
            load_lds16(gbase + (i * 512 + tid) * 8,
                       lbase + (i * 512 + wid * 64) * 8);
        }
    };

    stage(wt1, &w1c[0][0]);
    stage(wt2, &w2c[0][0]);

    // b1 -> LDS (avoids in-loop global loads that would drain vmcnt)
    b1s[tid]       = b1[tid];
    b1s[tid + 512] = b1[tid + 512];

    // x fragments: each wave owns 16 rows -> 8 frags (32 VGPR)
    bf16x8 xf[8];
    {
        const float* xr = xin + (rowbase + wid * 16 + l15) * 256;
        #pragma unroll
        for (int ks = 0; ks < 8; ++ks) {
            float4 a0 = *(const float4*)(xr + ks * 32 + g * 8);
            float4 a1 = *(const float4*)(xr + ks * 32 + g * 8 + 4);
            xf[ks] = pack8(a0, a1);
        }
    }

    f32x4 oacc[4][4] = {};

    __syncthreads();   // prologue: b1s visible + stage(0) drained (once)

    for (int hc = 0; hc < 32; ++hc) {
        const int cur = hc & 1;

        if (hc < 31) {
            stage(wt1 + (size_t)(hc + 1) * 8192, &w1c[cur ^ 1][0]);
            stage(wt2 + (size_t)(hc + 1) * 8192, &w2c[cur ^ 1][0]);
            asm volatile("s_waitcnt vmcnt(4)" ::: "memory");   // chunk hc ready
        } else {
            asm volatile("s_waitcnt vmcnt(0)" ::: "memory");
        }
        __builtin_amdgcn_s_barrier();
        __builtin_amdgcn_sched_barrier(0);

        // ---- h-phase: 128x32 = x @ w1c; wave wid owns rows wid*16..+16 ----
        f32x4 hacc[2] = {};
        #pragma unroll
        for (int ks = 0; ks < 8; ++ks) {
            bf16x8 b0  = *(const bf16x8*)&w1c[cur][(ks * 2 + 0) * 512 + fb];
            bf16x8 b1f = *(const bf16x8*)&w1c[cur][(ks * 2 + 1) * 512 + fb];
            hacc[0] = mfma_bf16(xf[ks], b0,  hacc[0]);
            hacc[1] = mfma_bf16(xf[ks], b1f, hacc[1]);
        }

        // hoist w2 frags (ready since top barrier): latency hides under GELU
        bf16x8 bF[4];
        #pragma unroll
        for (int t = 0; t < 4; ++t)
            bF[t] = *(const bf16x8*)&w2c[cur][(wno * 4 + t) * 512 + fb];

        // ---- bias (LDS) + GELU -> bf16 -> Hs ----
        #pragma unroll
        for (int nt = 0; nt < 2; ++nt) {
            int coll = nt * 16 + l15;
            float bias = b1s[hc * 32 + coll];
            #pragma unroll
            for (int r = 0; r < 4; ++r) {
                float vv = gelu_erf(hacc[nt][r] + bias);
                Hs[wid * 16 + g * 4 + r][coll] = f2bf(vv);
            }
        }
        asm volatile("s_waitcnt lgkmcnt(0)" ::: "memory");     // Hs writes done
        __builtin_amdgcn_s_barrier();                          // no vm drain!
        __builtin_amdgcn_sched_barrier(0);

        // ---- out-phase: oacc += h(128x32) @ w2c(32x256), waves 2Mx4N ----
        bf16x8 aF[4];
        #pragma unroll
        for (int t = 0; t < 4; ++t)
            aF[t] = *(const bf16x8*)&Hs[wmo * 64 + t * 16 + l15][g * 8];
        #pragma unroll
        for (int mt = 0; mt < 4; ++mt)
            #pragma unroll
            for (int nt = 0; nt < 4; ++nt)
                oacc[mt][nt] = mfma_bf16(aF[mt], bF[nt], oacc[mt][nt]);
    }

    // ---- epilogue: out = oacc + b2 + residual ----
    #pragma unroll
    for (int nt = 0; nt < 4; ++nt) {
        int col = wno * 64 + nt * 16 + l15;
        float bias = b2[col];
        #pragma unroll
        for (int mt = 0; mt < 4; ++mt) {
            #pragma unroll
            for (int r = 0; r < 4; ++r) {
                size_t idx = (rowbase + wmo * 64 + mt * 16 + g * 4 + r) * 256 + col;
                xio[idx] = oacc[mt][nt][r] + bias + xio[idx];
            }
        }
    }
}

// ---------------------------------------------------------------------------
extern "C" void kernel_launch(void* const* d_in, const int* in_sizes, int n_in,
                              void* d_out, int out_size, void* d_ws, size_t ws_size,
                              hipStream_t stream)
{
    const float* q    = (const float*)d_in[0];
    const float* k    = (const float*)d_in[1];
    const float* v    = (const float*)d_in[2];
    const float* mask = (const float*)d_in[3];
    const float* w1   = (const float*)d_in[6];
    const float* b1   = (const float*)d_in[7];
    const float* w2   = (const float*)d_in[8];
    const float* b2   = (const float*)d_in[9];

    float* xio = (float*)d_out;

    unsigned short* wt1 = (unsigned short*)d_ws;                 // 32 chunks x 16 KB
    unsigned short* wt2 = wt1 + (size_t)1024 * 256;

    prep_w1<<<dim3(4, 16), 256, 0, stream>>>(w1, wt1);
    prep_w2<<<dim3(4, 16), 256, 0, stream>>>(w2, wt2);

    attn_kernel<<<8192, 256, 0, stream>>>(q, k, v, mask, xio);

    mlp_fused<<<512, 512, 0, stream>>>(xio, xio, wt1, b1, wt2, b2);
}

// Round 9
// 169.958 us; speedup vs baseline: 3.2318x; 3.2318x over previous
//
#include <hip/hip_runtime.h>
#include <hip/hip_bf16.h>
#include <cstdint>
#include <cstddef>

typedef __attribute__((ext_vector_type(8))) short bf16x8;   // 8 bf16 in 4 VGPRs
typedef __attribute__((ext_vector_type(4))) float f32x4;

// Native bf16 convert (RNE) — compiler emits v_cvt_pk_bf16_f32 for pairs.
static __device__ __forceinline__ unsigned short f2bf(float f) {
    __hip_bfloat16 h = __float2bfloat16(f);
    return *reinterpret_cast<unsigned short*>(&h);
}

static __device__ __forceinline__ f32x4 mfma_bf16(bf16x8 a, bf16x8 b, f32x4 c) {
    return __builtin_amdgcn_mfma_f32_16x16x32_bf16(a, b, c, 0, 0, 0);
}

static __device__ __forceinline__ bf16x8 pack8(float4 a, float4 b) {
    bf16x8 f;
    f[0]=(short)f2bf(a.x); f[1]=(short)f2bf(a.y); f[2]=(short)f2bf(a.z); f[3]=(short)f2bf(a.w);
    f[4]=(short)f2bf(b.x); f[5]=(short)f2bf(b.y); f[6]=(short)f2bf(b.z); f[7]=(short)f2bf(b.w);
    return f;
}

// Branchless exact-erf GELU (A&S 7.1.26, |erf err| < 1.5e-7).
static __device__ __forceinline__ float gelu_erf(float v) {
    float s = v * 0.70710678118654752f;
    float a = fabsf(s);
    float t = __builtin_amdgcn_rcpf(1.0f + 0.3275911f * a);
    float poly = ((((1.061405429f * t - 1.453152027f) * t + 1.421413741f) * t
                   - 0.284496736f) * t + 0.254829592f) * t;
    float e = 1.0f - poly * __expf(-a * a);
    float erfv = copysignf(e, s);
    return 0.5f * v * (1.0f + erfv);
}

// async 16B global -> LDS (linear dest: wave-uniform base + lane*16)
static __device__ __forceinline__ void load_lds16(const unsigned short* g, unsigned short* l) {
    __builtin_amdgcn_global_load_lds(
        (const __attribute__((address_space(1))) unsigned int*)g,
        (__attribute__((address_space(3))) unsigned int*)l, 16, 0, 0);
}

// ---------------------------------------------------------------------------
// Attention (at its HBM floor ~43us): one block per (window, head).
// ---------------------------------------------------------------------------
__global__ __launch_bounds__(256) void attn_kernel(
    const float* __restrict__ q, const float* __restrict__ k,
    const float* __restrict__ v, const float* __restrict__ mask,
    float* __restrict__ xout)
{
    __shared__ unsigned short Qs[64][40];
    __shared__ unsigned short Ks[64][40];
    __shared__ unsigned short Vt[32][72];
    __shared__ unsigned short Ps[64][72];

    const int tid  = threadIdx.x;
    const int b    = blockIdx.x >> 3;
    const int h    = blockIdx.x & 7;
    const int lane = tid & 63;
    const int l15  = lane & 15;
    const int g    = lane >> 4;
    const int w    = tid >> 6;

    {
        int row = tid >> 2;
        int seg = tid & 3;
        size_t base = ((size_t)(b * 64 + row)) * 256 + h * 32 + seg * 8;

        float4 a0 = *(const float4*)(q + base);
        float4 a1 = *(const float4*)(q + base + 4);
        unsigned short* p = &Qs[row][seg * 8];
        p[0]=f2bf(a0.x); p[1]=f2bf(a0.y); p[2]=f2bf(a0.z); p[3]=f2bf(a0.w);
        p[4]=f2bf(a1.x); p[5]=f2bf(a1.y); p[6]=f2bf(a1.z); p[7]=f2bf(a1.w);

        a0 = *(const float4*)(k + base);
        a1 = *(const float4*)(k + base + 4);
        p = &Ks[row][seg * 8];
        p[0]=f2bf(a0.x); p[1]=f2bf(a0.y); p[2]=f2bf(a0.z); p[3]=f2bf(a0.w);
        p[4]=f2bf(a1.x); p[5]=f2bf(a1.y); p[6]=f2bf(a1.z); p[7]=f2bf(a1.w);

        a0 = *(const float4*)(v + base);
        a1 = *(const float4*)(v + base + 4);
        int c = seg * 8;
        Vt[c + 0][row] = f2bf(a0.x);
        Vt[c + 1][row] = f2bf(a0.y);
        Vt[c + 2][row] = f2bf(a0.z);
        Vt[c + 3][row] = f2bf(a0.w);
        Vt[c + 4][row] = f2bf(a1.x);
        Vt[c + 5][row] = f2bf(a1.y);
        Vt[c + 6][row] = f2bf(a1.z);
        Vt[c + 7][row] = f2bf(a1.w);
    }
    __syncthreads();

    f32x4 s[4];
    {
        bf16x8 aQ = *(const bf16x8*)&Qs[w * 16 + l15][g * 8];
        #pragma unroll
        for (int ct = 0; ct < 4; ++ct) {
            bf16x8 bK = *(const bf16x8*)&Ks[ct * 16 + l15][g * 8];
            f32x4 z = {0.f, 0.f, 0.f, 0.f};
            s[ct] = mfma_bf16(aQ, bK, z);
        }
    }

    const float* mbase = mask + (size_t)(b & 63) * 4096;
    const float INV = 0.17677669529663688f;
    float rsum[4];
    #pragma unroll
    for (int r = 0; r < 4; ++r) {
        int row = w * 16 + g * 4 + r;
        float pr[4];
        #pragma unroll
        for (int ct = 0; ct < 4; ++ct)
            pr[ct] = (s[ct][r] + mbase[row * 64 + ct * 16 + l15]) * INV;
        float m = fmaxf(fmaxf(pr[0], pr[1]), fmaxf(pr[2], pr[3]));
        #pragma unroll
        for (int off = 1; off < 16; off <<= 1)
            m = fmaxf(m, __shfl_xor(m, off));
        float sum = 0.f;
        #pragma unroll
        for (int ct = 0; ct < 4; ++ct) { pr[ct] = __expf(pr[ct] - m); sum += pr[ct]; }
        #pragma unroll
        for (int off = 1; off < 16; off <<= 1)
            sum += __shfl_xor(sum, off);
        rsum[r] = sum;
        #pragma unroll
        for (int ct = 0; ct < 4; ++ct)
            Ps[row][ct * 16 + l15] = f2bf(pr[ct]);
    }

    f32x4 o[2] = {};
    #pragma unroll
    for (int ks = 0; ks < 2; ++ks) {
        bf16x8 pa = *(const bf16x8*)&Ps[w * 16 + l15][ks * 32 + g * 8];
        #pragma unroll
        for (int n = 0; n < 2; ++n) {
            bf16x8 vb = *(const bf16x8*)&Vt[n * 16 + l15][ks * 32 + g * 8];
            o[n] = mfma_bf16(pa, vb, o[n]);
        }
    }

    #pragma unroll
    for (int n = 0; n < 2; ++n) {
        #pragma unroll
        for (int r = 0; r < 4; ++r) {
            int row = w * 16 + g * 4 + r;
            xout[((size_t)(b * 64 + row)) * 256 + h * 32 + n * 16 + l15] =
                o[n][r] / rsum[r];
        }
    }
}

// ---------------------------------------------------------------------------
// Weight prep, FRAGMENT-ORDERED, hidden-chunk = 32 (unchanged, proven).
// ---------------------------------------------------------------------------
__global__ __launch_bounds__(256) void prep_w1(const float* __restrict__ src,
                                               unsigned short* __restrict__ dst)
{
    __shared__ float tile[64][65];              // [k_local][n_local]
    const int kt = blockIdx.x, nb = blockIdx.y;
    const int t = threadIdx.x;
    const int r0 = t >> 4, c4 = (t & 15) * 4;
    #pragma unroll
    for (int p = 0; p < 4; ++p) {
        int kk = r0 + p * 16;
        float4 d = *(const float4*)(src + (size_t)(kt * 64 + kk) * 1024 + nb * 64 + c4);
        tile[kk][c4+0]=d.x; tile[kk][c4+1]=d.y; tile[kk][c4+2]=d.z; tile[kk][c4+3]=d.w;
    }
    __syncthreads();
    #pragma unroll
    for (int i = 0; i < 2; ++i) {
        int f = t + 256 * i;                    // 0..511
        int ksl = f >> 8;
        int ntg = (f >> 6) & 3;
        int gv  = (f >> 4) & 3;
        int l15v = f & 15;
        int n_local = ntg * 16 + l15v;
        int k_local = ksl * 32 + gv * 8;
        int c  = nb * 2 + (ntg >> 1);
        int nt = ntg & 1;
        int ks = kt * 2 + ksl;
        unsigned short tmp[8];
        #pragma unroll
        for (int e = 0; e < 8; ++e) tmp[e] = f2bf(tile[k_local + e][n_local]);
        size_t off = (size_t)c * 8192 + (size_t)((ks * 2 + nt) * 512)
                   + (gv * 16 + l15v) * 8;
        *(bf16x8*)(dst + off) = *(const bf16x8*)tmp;
    }
}

__global__ __launch_bounds__(256) void prep_w2(const float* __restrict__ src,
                                               unsigned short* __restrict__ dst)
{
    __shared__ float tile[64][65];              // [k_local][c_local]
    const int ob = blockIdx.x, kb = blockIdx.y;
    const int t = threadIdx.x;
    const int r0 = t >> 4, c4 = (t & 15) * 4;
    #pragma unroll
    for (int p = 0; p < 4; ++p) {
        int kk = r0 + p * 16;
        float4 d = *(const float4*)(src + (size_t)(kb * 64 + kk) * 256 + ob * 64 + c4);
        tile[kk][c4+0]=d.x; tile[kk][c4+1]=d.y; tile[kk][c4+2]=d.z; tile[kk][c4+3]=d.w;
    }
    __syncthreads();
    #pragma unroll
    for (int i = 0; i < 2; ++i) {
        int f = t + 256 * i;
        int ksl = f >> 8;
        int tq  = (f >> 6) & 3;
        int gv  = (f >> 4) & 3;
        int l15v = f & 15;
        int c_local = tq * 16 + l15v;
        int k_local = ksl * 32 + gv * 8;
        int c = kb * 2 + ksl;
        unsigned short tmp[8];
        #pragma unroll
        for (int e = 0; e < 8; ++e) tmp[e] = f2bf(tile[k_local + e][c_local]);
        size_t off = (size_t)c * 8192 + (size_t)((ob * 4 + tq) * 512)
                   + (gv * 16 + l15v) * 8;
        *(bf16x8*)(dst + off) = *(const bf16x8*)tmp;
    }
}

// ---------------------------------------------------------------------------
// Fused MLP v7: wave-private h -> ONE __syncthreads per chunk, no inline asm.
// Each wave owns 16 rows end-to-end: h-MFMA (16), GELU (8 vals/lane),
// same-wave Hs round-trip (lgkmcnt-ordered by compiler, no barrier),
// out-MFMA over all 16 col-tiles (16), oacc[16] f32x4.
// ---------------------------------------------------------------------------
__global__ __launch_bounds__(512, 4) void mlp_fused(
    const float* __restrict__ xin, float* __restrict__ xio,
    const unsigned short* __restrict__ wt1, const float* __restrict__ b1,
    const unsigned short* __restrict__ wt2, const float* __restrict__ b2)
{
    __shared__ unsigned short w1c[2][8192];     // 16 KB per buf, frag-ordered
    __shared__ unsigned short w2c[2][8192];
    __shared__ unsigned short Hs[8][16][36];    // wave-private, 72B row pitch
    __shared__ float b1s[1024];

    const int tid  = threadIdx.x;
    const int lane = tid & 63;
    const int l15  = lane & 15;
    const int g    = lane >> 4;
    const int wid  = tid >> 6;                  // 0..7
    const int fb   = (g * 16 + l15) * 8;        // frag offset: wave-contiguous 1KB

    const size_t rowbase = (size_t)blockIdx.x * 128;

    auto stage = [&](const unsigned short* gbase, unsigned short* lbase) {
        #pragma unroll
        for (int i = 0; i < 2; ++i) {
            load_lds16(gbase + (i * 512 + tid) * 8,
                       lbase + (i * 512 + wid * 64) * 8);
        }
    };

    stage(wt1, &w1c[0][0]);
    stage(wt2, &w2c[0][0]);

    // b1 -> LDS once
    b1s[tid]       = b1[tid];
    b1s[tid + 512] = b1[tid + 512];

    // x fragments: each wave owns 16 rows -> 8 frags (32 VGPR)
    bf16x8 xf[8];
    {
        const float* xr = xin + (rowbase + wid * 16 + l15) * 256;
        #pragma unroll
        for (int ks = 0; ks < 8; ++ks) {
            float4 a0 = *(const float4*)(xr + ks * 32 + g * 8);
            float4 a1 = *(const float4*)(xr + ks * 32 + g * 8 + 4);
            xf[ks] = pack8(a0, a1);
        }
    }

    f32x4 oacc[16] = {};   // own 16 rows x 256 cols

    for (int hc = 0; hc < 32; ++hc) {
        const int cur = hc & 1;
        __syncthreads();   // drains chunk-hc DMA; frees buf cur^1 for prefetch

        if (hc < 31) {
            stage(wt1 + (size_t)(hc + 1) * 8192, &w1c[cur ^ 1][0]);
            stage(wt2 + (size_t)(hc + 1) * 8192, &w2c[cur ^ 1][0]);
        }

        // ---- h-phase: own 16 rows x 32 hidden ----
        f32x4 hacc[2] = {};
        #pragma unroll
        for (int ks = 0; ks < 8; ++ks) {
            bf16x8 b0  = *(const bf16x8*)&w1c[cur][(ks * 2 + 0) * 512 + fb];
            bf16x8 b1f = *(const bf16x8*)&w1c[cur][(ks * 2 + 1) * 512 + fb];
            hacc[0] = mfma_bf16(xf[ks], b0,  hacc[0]);
            hacc[1] = mfma_bf16(xf[ks], b1f, hacc[1]);
        }

        // ---- bias + GELU -> bf16 -> wave-private Hs (no barrier needed) ----
        #pragma unroll
        for (int nt = 0; nt < 2; ++nt) {
            int coll = nt * 16 + l15;
            float bias = b1s[hc * 32 + coll];
            #pragma unroll
            for (int r = 0; r < 4; ++r) {
                float vv = gelu_erf(hacc[nt][r] + bias);
                Hs[wid][g * 4 + r][coll] = f2bf(vv);
            }
        }

        // ---- out-phase: own h frag (1 b128) x 16 w2 col-tiles ----
        bf16x8 aH = *(const bf16x8*)&Hs[wid][l15][g * 8];
        #pragma unroll
        for (int n = 0; n < 16; ++n) {
            bf16x8 bF = *(const bf16x8*)&w2c[cur][n * 512 + fb];
            oacc[n] = mfma_bf16(aH, bF, oacc[n]);
        }
    }

    // ---- epilogue: out = oacc + b2 + residual (own 16 rows) ----
    #pragma unroll
    for (int n = 0; n < 16; ++n) {
        int col = n * 16 + l15;
        float bias = b2[col];
        #pragma unroll
        for (int r = 0; r < 4; ++r) {
            size_t idx = (rowbase + wid * 16 + g * 4 + r) * 256 + col;
            xio[idx] = oacc[n][r] + bias + xio[idx];
        }
    }
}

// ---------------------------------------------------------------------------
extern "C" void kernel_launch(void* const* d_in, const int* in_sizes, int n_in,
                              void* d_out, int out_size, void* d_ws, size_t ws_size,
                              hipStream_t stream)
{
    const float* q    = (const float*)d_in[0];
    const float* k    = (const float*)d_in[1];
    const float* v    = (const float*)d_in[2];
    const float* mask = (const float*)d_in[3];
    const float* w1   = (const float*)d_in[6];
    const float* b1   = (const float*)d_in[7];
    const float* w2   = (const float*)d_in[8];
    const float* b2   = (const float*)d_in[9];

    float* xio = (float*)d_out;

    unsigned short* wt1 = (unsigned short*)d_ws;                 // 32 chunks x 16 KB
    unsigned short* wt2 = wt1 + (size_t)1024 * 256;

    prep_w1<<<dim3(4, 16), 256, 0, stream>>>(w1, wt1);
    prep_w2<<<dim3(4, 16), 256, 0, stream>>>(w2, wt2);

    attn_kernel<<<8192, 256, 0, stream>>>(q, k, v, mask, xio);

    mlp_fused<<<512, 512, 0, stream>>>(xio, xio, wt1, b1, wt2, b2);
}